// Round 3
// baseline (658.493 us; speedup 1.0000x reference)
//
#include <hip/hip_runtime.h>
#include <math.h>

#define NB 16
#define NH 1024
#define NT 4096
#define CD 8
#define CS 1024
#define NBT (NB*NT)

#define HCA 16            // h-chunks (64 h each)
#define HCH (NH/HCA)      // 64 h per chunk
#define TCA 2             // t-chunks per b
#define TTA (NT/TCA)      // 2048 t per chunk
#define MARGIN 1e-3f      // fp32 top-2 margin; fp32 dist abs error ~6e-6 -> 80x safety

// ---------------- K0: prepare tables in workspace ----------------
__global__ __launch_bounds__(256) void k0_prep(
    const float* __restrict__ w,      // in_proj_w [CD][NH]
    const float* __restrict__ bias,   // in_proj_b [CD]
    const float* __restrict__ cb,     // codebook [CS][CD]
    double* __restrict__ Wt,          // out: [NH][CD] fp64
    double* __restrict__ biasd,       // out: [CD]
    double* __restrict__ cbn,         // out: normalized codebook [CS][CD] fp64
    double* __restrict__ cbn2,        // out: sum(cbn^2) [CS] fp64
    float*  __restrict__ cbnf,        // out: normalized codebook fp32 [CS][CD]
    float*  __restrict__ cbn2f,       // out: sum fp32 [CS]
    double* __restrict__ lossacc)     // zeroed
{
    int g = blockIdx.x * 256 + threadIdx.x;   // grid = 32*256 = 8192
    if (g < CD * NH) {
        int h = g >> 3, d = g & 7;
        Wt[g] = (double)w[d * NH + h];
    }
    if (g < CS) {
        double v[CD];
        double s = 0.0;
        #pragma unroll
        for (int j = 0; j < CD; j++) { v[j] = (double)cb[g * CD + j]; s += v[j] * v[j]; }
        double n = sqrt(s);
        double m = fmax(n, 1e-12);
        double s2 = 0.0;
        #pragma unroll
        for (int j = 0; j < CD; j++) {
            double q = v[j] / m;              // replicate x / max(n,eps) exactly
            cbn[g * CD + j] = q;
            cbnf[g * CD + j] = (float)q;
            s2 += q * q;
        }
        cbn2[g] = s2;
        cbn2f[g] = (float)s2;
    }
    if (g < CD) biasd[g] = (double)bias[g];
    if (g == 0) *lossacc = 0.0;
}

// ---------------- K1: partial proj over a 64-h band ----------------
// grid = (b, tc, hc) = 16*2*16 = 512 blocks, 512 threads, no LDS, no barriers.
// Per h-row the block reads 8 KB CONTIGUOUS (512 lanes * float4) -> DRAM-page friendly.
// Partials land in the first 33.5 MB of the `out` region (scratch; K4 overwrites it).
__global__ __launch_bounds__(512, 4) void k1_partial(
    const float*  __restrict__ x,     // hidden [NB][NH][NT]
    const double* __restrict__ Wt,    // [NH][CD]
    float* __restrict__ ps)           // out: partials [512 blk][CD][TTA] fp32 (scratch in d_out)
{
    const int tid = threadIdx.x;            // 0..511
    const int bid = blockIdx.x;             // 0..511
    const int hc  = bid & (HCA - 1);
    const int tc  = (bid >> 4) & (TCA - 1);
    const int b   = bid >> 5;
    const int h0  = hc * HCH;
    const int t0  = tc * TTA + tid * 4;

    const float* xp = x + ((size_t)b * NH + h0) * NT + t0;

    double acc[CD][4];
    #pragma unroll
    for (int d = 0; d < CD; d++)
        #pragma unroll
        for (int j = 0; j < 4; j++) acc[d][j] = 0.0;

    for (int i = 0; i < HCH; i += 4) {
        float4 xv[4];
        #pragma unroll
        for (int j = 0; j < 4; j++) xv[j] = *(const float4*)(xp + (size_t)(i + j) * NT);
        #pragma unroll
        for (int j = 0; j < 4; j++) {
            const double* wr = Wt + (size_t)(h0 + i + j) * CD;   // wave-uniform -> scalar loads
            const double x0 = (double)xv[j].x;
            const double x1 = (double)xv[j].y;
            const double x2 = (double)xv[j].z;
            const double x3 = (double)xv[j].w;
            #pragma unroll
            for (int d = 0; d < CD; d++) {
                acc[d][0] = fma(x0, wr[d], acc[d][0]);
                acc[d][1] = fma(x1, wr[d], acc[d][1]);
                acc[d][2] = fma(x2, wr[d], acc[d][2]);
                acc[d][3] = fma(x3, wr[d], acc[d][3]);
            }
        }
    }

    // write fp32 partials: per d the block writes 8 KB contiguous
    float* pp = ps + ((size_t)bid * CD) * TTA + tid * 4;
    #pragma unroll
    for (int d = 0; d < CD; d++) {
        float4 o;
        o.x = (float)acc[d][0]; o.y = (float)acc[d][1];
        o.z = (float)acc[d][2]; o.w = (float)acc[d][3];
        *(float4*)(pp + (size_t)d * TTA) = o;
    }
}

// ---------------- K2: reduce partials -> proj, argmax, q_st, loss ----------------
// one thread per (b,t) row; 256 blocks * 256 threads. No LDS.
__global__ __launch_bounds__(256) void k2_mid(
    const float*  __restrict__ ps,     // [512][CD][TTA] (scratch in d_out)
    const double* __restrict__ biasd,  // [CD]
    const double* __restrict__ cbn,    // [CS][CD] fp64 (fallback)
    const double* __restrict__ cbn2,   // [CS]
    const float*  __restrict__ cbnf,   // [CS][CD] fp32
    const float*  __restrict__ cbn2f,  // [CS]
    const float*  __restrict__ cb,     // original codebook fp32 [CS][CD]
    double* __restrict__ lossacc,
    float* __restrict__ idxf,          // [NBT]
    float* __restrict__ projf,         // [NB][CD][NT]
    float* __restrict__ qf)            // [NB][CD][NT] straight-through values (in ws)
{
    const int tid = threadIdx.x;
    const int g   = blockIdx.x * 256 + tid;   // row 0..65535
    const int b   = g >> 12;
    const int t   = g & (NT - 1);
    const int tc  = t >> 11;
    const int tl  = t & (TTA - 1);

    // sum 16 hc-partials per d in fp64 (fixed ascending order -> deterministic)
    const float* pbase = ps + ((size_t)(b * TCA + tc) * HCA) * CD * TTA + tl;
    double p[CD];
    #pragma unroll
    for (int d = 0; d < CD; d++) {
        double s = 0.0;
        #pragma unroll
        for (int hc = 0; hc < HCA; hc++) s += (double)pbase[((size_t)hc * CD + d) * TTA];
        s += biasd[d];
        p[d] = s;
    }

    float pf[CD];
    #pragma unroll
    for (int d = 0; d < CD; d++) {
        pf[d] = (float)p[d];
        projf[((size_t)b * CD + d) * NT + t] = pf[d];
    }

    double s2 = 0.0;
    #pragma unroll
    for (int d = 0; d < CD; d++) s2 += p[d] * p[d];
    const double m = fmax(sqrt(s2), 1e-12);
    float pn[CD];
    #pragma unroll
    for (int d = 0; d < CD; d++) pn[d] = (float)(2.0 * (p[d] / m));

    // fp32 scan over all codes, 2-way ILP, strict > keeps first max; track top-2
    float best = -3.4e38f, second = -3.4e38f;
    int bi = 0;
    for (int c = 0; c < CS; c += 2) {
        const float* cr0 = cbnf + (size_t)c * CD;        // uniform -> scalar loads
        const float* cr1 = cr0 + CD;
        float dot0 = cbn2f[c];
        float dot1 = cbn2f[c + 1];
        #pragma unroll
        for (int d = 0; d < CD; d++) {
            dot0 = fmaf(pn[d], cr0[d], dot0);
            dot1 = fmaf(pn[d], cr1[d], dot1);
        }
        second = fmaxf(second, fminf(dot0, best));
        if (dot0 > best) { best = dot0; bi = c; }
        second = fmaxf(second, fminf(dot1, best));
        if (dot1 > best) { best = dot1; bi = c + 1; }
    }

    // wave-cooperative fp64 recheck for near-ties (bit-identical to original fp64 rule)
    const int lane = tid & 63;
    unsigned long long mask = __ballot((best - second) <= MARGIN);
    while (mask) {
        const int src = __ffsll(mask) - 1;
        mask &= mask - 1;
        double q[CD];
        #pragma unroll
        for (int d = 0; d < CD; d++) q[d] = __shfl(p[d], src, 64);
        double qs = 0.0;
        #pragma unroll
        for (int d = 0; d < CD; d++) qs += q[d] * q[d];
        const double qm = fmax(sqrt(qs), 1e-12);
        double qn[CD];
        #pragma unroll
        for (int d = 0; d < CD; d++) qn[d] = 2.0 * (q[d] / qm);
        double bv = -1e300;
        int bidx = 0;
        for (int k = 0; k < CS / 64; k++) {
            const int c = k * 64 + lane;               // per-lane ascending scan
            const double* cr = cbn + (size_t)c * CD;
            double dot = cbn2[c];
            #pragma unroll
            for (int d = 0; d < CD; d++) dot = fma(qn[d], cr[d], dot);
            if (dot > bv) { bv = dot; bidx = c; }
        }
        #pragma unroll
        for (int off = 32; off; off >>= 1) {           // global first-max: max val, tie -> min idx
            const double ov = __shfl_xor(bv, off, 64);
            const int    oi = __shfl_xor(bidx, off, 64);
            if (ov > bv || (ov == bv && oi < bidx)) { bv = ov; bidx = oi; }
        }
        if (lane == src) bi = bidx;
    }

    // finalize row
    idxf[g] = (float)bi;
    const float* qr = cb + (size_t)bi * CD;
    double ls = 0.0;
    #pragma unroll
    for (int d = 0; d < CD; d++) {
        const float cf = qr[d];
        const float qv = pf[d] + (cf - pf[d]);         // straight-through forward value
        qf[((size_t)b * CD + d) * NT + t] = qv;
        const float df = pf[d] - cf;
        ls += (double)(df * df);
    }
    #pragma unroll
    for (int off = 32; off; off >>= 1) ls += __shfl_xor(ls, off, 64);
    if (lane == 0) atomicAdd(lossacc, ls);
}

// ---------------- K4: out = q_st @ Wout^T + b ----------------
// grid = (b, tc, hc) = 512 blocks, 512 threads; per h-row 8 KB contiguous float4 stores.
// Overwrites the entire out region (including the ps scratch at its head).
// Per-element rounding identical to previous passing version (fmaf chain over d, then += bias).
__global__ __launch_bounds__(512) void k4_out(
    const float*  __restrict__ qf,     // [NB][CD][NT] (in ws)
    const float*  __restrict__ wo,     // out_proj_w [NH][CD]
    const float*  __restrict__ bo,     // out_proj_b [NH]
    const double* __restrict__ lossacc,
    float* __restrict__ out,           // [NB][NH][NT]
    float* __restrict__ lossout)       // 2 floats
{
    if (blockIdx.x == 0 && threadIdx.x == 0) {
        const float v = (float)(*lossacc / (double)((size_t)NB * CD * NT));
        lossout[0] = v;   // commitment_loss
        lossout[1] = v;   // codebook_loss (identical forward value)
    }

    const int tid = threadIdx.x;
    const int bid = blockIdx.x;
    const int hc  = bid & (HCA - 1);
    const int tc  = (bid >> 4) & (TCA - 1);
    const int b   = bid >> 5;
    const int h0  = hc * HCH;
    const int t0  = tc * TTA + tid * 4;

    float q[CD][4];
    #pragma unroll
    for (int d = 0; d < CD; d++) {
        const float4 v = *(const float4*)(qf + ((size_t)b * CD + d) * NT + t0);
        q[d][0] = v.x; q[d][1] = v.y; q[d][2] = v.z; q[d][3] = v.w;
    }

    float* op = out + ((size_t)b * NH + h0) * NT + t0;
    for (int i = 0; i < HCH; i++) {
        const float* wr = wo + (size_t)(h0 + i) * CD;   // wave-uniform -> scalar loads
        const float bh = bo[h0 + i];
        float o0 = 0.f, o1 = 0.f, o2 = 0.f, o3 = 0.f;
        #pragma unroll
        for (int d = 0; d < CD; d++) {
            o0 = fmaf(q[d][0], wr[d], o0);
            o1 = fmaf(q[d][1], wr[d], o1);
            o2 = fmaf(q[d][2], wr[d], o2);
            o3 = fmaf(q[d][3], wr[d], o3);
        }
        o0 += bh; o1 += bh; o2 += bh; o3 += bh;
        *(float4*)(op + (size_t)i * NT) = make_float4(o0, o1, o2, o3);
    }
}

// ---------------- launch ----------------
extern "C" void kernel_launch(void* const* d_in, const int* in_sizes, int n_in,
                              void* d_out, int out_size, void* d_ws, size_t ws_size,
                              hipStream_t stream) {
    const float* hidden = (const float*)d_in[0];
    const float* ipw    = (const float*)d_in[1];
    const float* ipb    = (const float*)d_in[2];
    const float* opw    = (const float*)d_in[3];
    const float* opb    = (const float*)d_in[4];
    const float* cb     = (const float*)d_in[5];

    float* out      = (float*)d_out;                    // [NB][NH][NT]
    float* loss_out = out + (size_t)NB * NH * NT;       // 2 scalars
    float* idxf     = loss_out + 2;                     // [NB*NT]
    float* projf    = idxf + NBT;                       // [NB][CD][NT]

    // ps partials (33.5 MB) live at the HEAD of the out region as scratch:
    // written by K1, read by K2, then fully overwritten by K4's final out writes.
    float* ps = out;

    // workspace: ~2.3 MB total (well under the ~4.6 MB proven available)
    double* Wt      = (double*)d_ws;                    // 8192 doubles
    double* biasd   = Wt + CD * NH;                     // 8
    double* cbn     = biasd + 8;                        // 8192
    double* cbn2    = cbn + (size_t)CS * CD;            // 1024
    double* lossacc = cbn2 + CS;                        // 1 (+7 pad)
    float*  cbnf    = (float*)(lossacc + 8);            // 8192 floats
    float*  cbn2f   = cbnf + (size_t)CS * CD;           // 1024 floats
    float*  qf      = cbn2f + CS;                       // NB*CD*NT floats = 2 MB (16B-aligned)

    k0_prep<<<32, 256, 0, stream>>>(ipw, ipb, cb, Wt, biasd, cbn, cbn2, cbnf, cbn2f,
                                    lossacc);
    k1_partial<<<NB * TCA * HCA, 512, 0, stream>>>(hidden, Wt, ps);
    k2_mid<<<NBT / 256, 256, 0, stream>>>(ps, biasd, cbn, cbn2, cbnf, cbn2f, cb,
                                          lossacc, idxf, projf, qf);
    k4_out<<<NB * TCA * HCA, 512, 0, stream>>>(qf, opw, opb, lossacc, out, loss_out);
}